// Round 13
// baseline (309.075 us; speedup 1.0000x reference)
//
#include <hip/hip_runtime.h>
#include <hip/hip_bf16.h>

typedef __attribute__((ext_vector_type(8))) short bf16x8;
typedef __attribute__((ext_vector_type(4))) float f32x4;

static constexpr int Tt = 2048;   // seq len
static constexpr int Cc = 1024;   // channels
static constexpr int Dd = 64;     // head dim
static constexpr int Mm = 8192;   // B*T

static constexpr size_t XN = (size_t)Mm * Cc;   // 8388608
static constexpr size_t WN = (size_t)Cc * Cc;   // 1048576

__device__ __forceinline__ void async_copy16(void* lds, const void* g) {
  __builtin_amdgcn_global_load_lds(
      (const __attribute__((address_space(1))) void*)g,
      (__attribute__((address_space(3))) void*)lds, 16, 0, 0);
}

__device__ __forceinline__ unsigned short f2bf(float f) {
  union { float f; unsigned int u; } v; v.f = f;
  unsigned int r = (v.u + 0x7fffu + ((v.u >> 16) & 1u)) >> 16;
  return (unsigned short)r;
}
__device__ __forceinline__ unsigned int pack2bf(float f0, float f1) {
  unsigned int b0 = __float_as_uint(f0) + 0x8000u;
  unsigned int b1 = __float_as_uint(f1) + 0x8000u;
  return (b1 & 0xffff0000u) | (b0 >> 16);
}
__device__ __forceinline__ uint4 ldconv_f32(const float* p) {
  float4 lo = *(const float4*)p;
  float4 hi = *(const float4*)(p + 4);
  uint4 r;
  r.x = pack2bf(lo.x, lo.y);
  r.y = pack2bf(lo.z, lo.w);
  r.z = pack2bf(hi.x, hi.y);
  r.w = pack2bf(hi.z, hi.w);
  return r;
}

// f32 -> bf16 pre-convert of X, Wq, Wk, Wv into d_out scratch (23.1MB < 33.5MB).
__global__ __launch_bounds__(256) void convert_all(
    const float* __restrict__ x, const float* __restrict__ wq,
    const float* __restrict__ wk, const float* __restrict__ wv,
    unsigned short* __restrict__ dst)
{
  const size_t i = ((size_t)blockIdx.x * 256 + threadIdx.x) * 8;
  const float* s; size_t off;
  if (i < XN)                { s = x;  off = 0; }
  else if (i < XN + WN)      { s = wq; off = XN; }
  else if (i < XN + 2 * WN)  { s = wk; off = XN + WN; }
  else                       { s = wv; off = XN + 2 * WN; }
  *(uint4*)(dst + i) = ldconv_f32(s + (i - off));
}

// NT GEMM, all-bf16 inputs, m97-pattern global_load_lds staging.
// MODE 0: bf16 out[m*Cc+n]*mult+bias. MODE 1 (V): bf16 out[(b*Cc+n)*Tt+t].
template <int MODE>
__device__ __forceinline__ void gemm_async_body(
    unsigned short* As, unsigned short* Bs,
    const unsigned short* __restrict__ A,
    const unsigned short* __restrict__ Bt,
    const float* __restrict__ bias,
    unsigned short* __restrict__ out, float mult)
{
  const int tid  = threadIdx.x;
  const int wave = tid >> 6;
  const int lane = tid & 63;
  const int m16  = lane & 15;
  const int quad = lane >> 4;
  const int row0 = blockIdx.x * 128;
  const int col0 = blockIdx.y * 128;
  const int wm = (wave >> 1) * 64;
  const int wn = (wave & 1) * 64;

  f32x4 acc[4][4] = {};

  const int c0 = tid, c1 = 256 + tid;
  const unsigned short* Ag0 = A  + (size_t)(row0 + (c0 >> 2)) * Cc + (c0 & 3) * 8;
  const unsigned short* Ag1 = A  + (size_t)(row0 + (c1 >> 2)) * Cc + (c1 & 3) * 8;
  const unsigned short* Bg0 = Bt + (size_t)(col0 + (c0 >> 2)) * Cc + (c0 & 3) * 8;
  const unsigned short* Bg1 = Bt + (size_t)(col0 + (c1 >> 2)) * Cc + (c1 & 3) * 8;
  char* Al0 = (char*)As + wave * 1024;
  char* Al1 = (char*)As + 4096 + wave * 1024;
  char* Bl0 = (char*)Bs + wave * 1024;
  char* Bl1 = (char*)Bs + 4096 + wave * 1024;

  for (int k0 = 0; k0 < Cc; k0 += 32) {
    __syncthreads();
    async_copy16(Al0, Ag0 + k0);
    async_copy16(Al1, Ag1 + k0);
    async_copy16(Bl0, Bg0 + k0);
    async_copy16(Bl1, Bg1 + k0);
    __syncthreads();
    bf16x8 af[4], bfr[4];
#pragma unroll
    for (int i = 0; i < 4; ++i)
      af[i] = *(const bf16x8*)(As + (wm + i * 16 + m16) * 32 + quad * 8);
#pragma unroll
    for (int j = 0; j < 4; ++j)
      bfr[j] = *(const bf16x8*)(Bs + (wn + j * 16 + m16) * 32 + quad * 8);
#pragma unroll
    for (int i = 0; i < 4; ++i)
#pragma unroll
      for (int j = 0; j < 4; ++j)
        acc[i][j] = __builtin_amdgcn_mfma_f32_16x16x32_bf16(af[i], bfr[j], acc[i][j], 0, 0, 0);
  }

#pragma unroll
  for (int i = 0; i < 4; ++i) {
    const int rbase = row0 + wm + i * 16 + quad * 4;
#pragma unroll
    for (int j = 0; j < 4; ++j) {
      const int col = col0 + wn + j * 16 + m16;
      const float bv = bias[col];
      if (MODE == 0) {
#pragma unroll
        for (int r = 0; r < 4; ++r)
          out[(size_t)(rbase + r) * Cc + col] = f2bf((acc[i][j][r] + bv) * mult);
      } else {
        const int t0 = rbase & (Tt - 1);
        const int b  = rbase >> 11;
        ushort4 pk;
        pk.x = f2bf(acc[i][j][0] + bv);
        pk.y = f2bf(acc[i][j][1] + bv);
        pk.z = f2bf(acc[i][j][2] + bv);
        pk.w = f2bf(acc[i][j][3] + bv);
        *(ushort4*)(out + (size_t)(b * Cc + col) * Tt + t0) = pk;
      }
    }
  }
}

__global__ __launch_bounds__(256) void qkv_gemm(
    const unsigned short* __restrict__ Xb,
    const unsigned short* __restrict__ Wqb, const float* __restrict__ bq,
    const unsigned short* __restrict__ Wkb, const float* __restrict__ bk,
    const unsigned short* __restrict__ Wvb, const float* __restrict__ bv,
    unsigned short* Qw, unsigned short* Kw, unsigned short* Vtw)
{
  __shared__ __align__(16) unsigned short smem[8192];
  const int z = blockIdx.z;
  // Q scale folds 1/sqrt(d) AND log2(e) so attention uses exp2 directly.
  if (z == 0)      gemm_async_body<0>(smem, smem + 4096, Xb, Wqb, bq, Qw, 0.125f * 1.44269504f);
  else if (z == 1) gemm_async_body<0>(smem, smem + 4096, Xb, Wkb, bk, Kw, 1.0f);
  else             gemm_async_body<1>(smem, smem + 4096, Xb, Wvb, bv, Vtw, 1.0f);
}

// Wave-per-strip-pair flash attention, transposed algebra, 16-ROW STRIPS:
//   128 strips x 64 bh / 2-per-wave = 4096 waves = 16/CU (2x round 12).
//   S^T = K.Q^T ; O^T = V^T.P^T with in-register P^T redistribution.
//   Pair (sidx, 127-sidx): (sidx>>2)+1 + ((127-sidx)>>2)+1 = 33 tiles/wave.
//   Block p (grid 16x64): heavy {127-4p-w}, light {4p+w}; maxH=32-p,
//   maxL=p+1 -> TOT=33 barriered tiles, constant across blocks.
//   Block-shared double-buffered swizzled K/V staging via global_load_lds.
__global__ __launch_bounds__(256) void attn_pair(
    const unsigned short* __restrict__ Q,
    const unsigned short* __restrict__ Kg,
    const unsigned short* __restrict__ Vt,
    unsigned short* __restrict__ Y)
{
  __shared__ __align__(16) unsigned short KV[2 * 8192];  // [buf][K 4096h | V 4096h]

  const int tid  = threadIdx.x;
  const int wave = tid >> 6;
  const int lane = tid & 63;
  const int m16  = lane & 15;
  const int quad = lane >> 4;

  const int p  = blockIdx.x;                  // 0..15
  const int bh = blockIdx.y;
  const int b = bh >> 4, h = bh & 15;

  const unsigned short* Kb = Kg + (size_t)(b * Tt) * Cc + h * Dd;
  const unsigned short* Vb = Vt + (size_t)(b * Cc + h * Dd) * Tt;

  const int maxH = 32 - p;
  const int TOT  = 33;                        // maxH + (p+1), constant
  const int chp  = quad ^ ((m16 >> 1) & 3);   // swizzled read channel
  const int slA  = m16 + ((quad & 1) << 5);   // P^T shuffle source lanes
  const int slB  = slA + 16;
  const int hi   = quad >> 1;                 // selects jn' = 2kk + hi

  int kkS[2], rrS[2], chdS[2];
#pragma unroll
  for (int ii = 0; ii < 2; ++ii) {
    const int cc = ii * 256 + tid;
    kkS[ii]  = cc >> 8;
    rrS[ii]  = (cc >> 2) & 63;
    chdS[ii] = (cc & 3) ^ ((rrS[ii] >> 1) & 3);
  }

  // phase-0 (heavy) strip state
  int sidx = 127 - 4 * p - wave;
  int qw = sidx * 16;
  int nk = (sidx >> 2) + 1;
  bf16x8 qf[2];
  {
    const unsigned short* Qb = Q + (size_t)(b * Tt + qw) * Cc + h * Dd;
#pragma unroll
    for (int kk = 0; kk < 2; ++kk)
      qf[kk] = *(const bf16x8*)(Qb + (size_t)m16 * Cc + kk * 32 + quad * 8);
  }
  f32x4 o[4] = {};
  float lsum = 0.f;

  auto writeout = [&](int qw_) {
    float l = lsum;
    l += __shfl_xor(l, 16, 64);
    l += __shfl_xor(l, 32, 64);
    const float inv = (l > 0.f) ? (1.0f / l) : 0.f;
    const int t = qw_ + m16;
    unsigned short* yp = Y + (size_t)(b * Tt + t) * Cc + h * Dd + quad * 4;
#pragma unroll
    for (int jn = 0; jn < 4; ++jn) {
      ushort4 pk;
      pk.x = f2bf(o[jn][0] * inv);
      pk.y = f2bf(o[jn][1] * inv);
      pk.z = f2bf(o[jn][2] * inv);
      pk.w = f2bf(o[jn][3] * inv);
      *(ushort4*)(yp + jn * 16) = pk;
    }
  };

  // prologue: stage tile g=0 into buf 0
  {
    char* KbufB = (char*)KV;
    char* VbufB = KbufB + 8192;
#pragma unroll
    for (int ii = 0; ii < 2; ++ii) {
      async_copy16(KbufB + ii * 4096 + wave * 1024,
                   Kb + (size_t)rrS[ii] * Cc + kkS[ii] * 32 + chdS[ii] * 8);
      async_copy16(VbufB + ii * 4096 + wave * 1024,
                   Vb + (size_t)rrS[ii] * Tt + kkS[ii] * 32 + chdS[ii] * 8);
    }
  }

  for (int g = 0; g < TOT; ++g) {
    if (g == maxH) {                          // heavy strip done -> switch to light
      writeout(qw);
      sidx = 4 * p + wave;
      qw = sidx * 16;
      nk = (sidx >> 2) + 1;
      const unsigned short* Qb = Q + (size_t)(b * Tt + qw) * Cc + h * Dd;
#pragma unroll
      for (int kk = 0; kk < 2; ++kk)
        qf[kk] = *(const bf16x8*)(Qb + (size_t)m16 * Cc + kk * 32 + quad * 8);
#pragma unroll
      for (int jn = 0; jn < 4; ++jn)
        o[jn] = f32x4{0.f, 0.f, 0.f, 0.f};
      lsum = 0.f;
    }
    const int kt  = (g < maxH) ? g : g - maxH;
    const int k0  = kt * 64;
    const int buf = g & 1;

    __syncthreads();                          // copies for g drained; prior LDS reads done
    if (g + 1 < TOT) {                        // prefetch tile g+1 into other buffer
      const int g1  = g + 1;
      const int kt1 = (g1 < maxH) ? g1 : g1 - maxH;
      const int k1  = kt1 * 64;
      char* KbufB = (char*)KV + (buf ^ 1) * 16384;
      char* VbufB = KbufB + 8192;
#pragma unroll
      for (int ii = 0; ii < 2; ++ii) {
        async_copy16(KbufB + ii * 4096 + wave * 1024,
                     Kb + (size_t)(k1 + rrS[ii]) * Cc + kkS[ii] * 32 + chdS[ii] * 8);
        async_copy16(VbufB + ii * 4096 + wave * 1024,
                     Vb + (size_t)rrS[ii] * Tt + k1 + kkS[ii] * 32 + chdS[ii] * 8);
      }
    }

    if (kt < nk) {                            // wave-uniform; barriers stay outside
      const unsigned short* Kbuf = KV + buf * 8192;
      const unsigned short* Vbuf = Kbuf + 4096;
      bf16x8 kf[2][4], vf[2][4];
#pragma unroll
      for (int kk = 0; kk < 2; ++kk)
#pragma unroll
        for (int jn = 0; jn < 4; ++jn) {
          kf[kk][jn] = *(const bf16x8*)(Kbuf + kk * 2048 + (jn * 16 + m16) * 32 + chp * 8);
          vf[kk][jn] = *(const bf16x8*)(Vbuf + kk * 2048 + (jn * 16 + m16) * 32 + chp * 8);
        }

      // S^T = K.Q^T : C-layout lane m16 = q, reg (jn,r) = key jn*16+quad*4+r
      f32x4 sv[4] = {};
#pragma unroll
      for (int kk = 0; kk < 2; ++kk)
#pragma unroll
        for (int jn = 0; jn < 4; ++jn)
          sv[jn] = __builtin_amdgcn_mfma_f32_16x16x32_bf16(kf[kk][jn], qf[kk], sv[jn], 0, 0, 0);

      if (k0 + 63 <= qw) {                    // fully unmasked: bare exp2
#pragma unroll
        for (int jn = 0; jn < 4; ++jn)
#pragma unroll
          for (int r = 0; r < 4; ++r) {
            const float pv = __builtin_exp2f(sv[jn][r]);
            sv[jn][r] = pv;
            lsum += pv;
          }
      } else {                                 // diagonal: causal mask
        const int qcol = qw + m16;
#pragma unroll
        for (int jn = 0; jn < 4; ++jn)
#pragma unroll
          for (int r = 0; r < 4; ++r) {
            const bool masked = (k0 + jn * 16 + quad * 4 + r > qcol);
            const float pv = masked ? 0.f : __builtin_exp2f(sv[jn][r]);
            sv[jn][r] = pv;
            lsum += pv;
          }
      }
      // pack key-pairs, redistribute to P^T B-fragments (in-register)
      unsigned int P2[4][2];
#pragma unroll
      for (int jn = 0; jn < 4; ++jn) {
        P2[jn][0] = pack2bf(sv[jn][0], sv[jn][1]);
        P2[jn][1] = pack2bf(sv[jn][2], sv[jn][3]);
      }
#pragma unroll
      for (int kk = 0; kk < 2; ++kk) {
        const int a0 = __shfl((int)P2[2 * kk][0],     slA, 64);
        const int b0 = __shfl((int)P2[2 * kk + 1][0], slA, 64);
        const int a1 = __shfl((int)P2[2 * kk][1],     slA, 64);
        const int b1 = __shfl((int)P2[2 * kk + 1][1], slA, 64);
        const int a2 = __shfl((int)P2[2 * kk][0],     slB, 64);
        const int b2 = __shfl((int)P2[2 * kk + 1][0], slB, 64);
        const int a3 = __shfl((int)P2[2 * kk][1],     slB, 64);
        const int b3 = __shfl((int)P2[2 * kk + 1][1], slB, 64);
        uint4 u;
        u.x = (unsigned int)(hi ? b0 : a0);
        u.y = (unsigned int)(hi ? b1 : a1);
        u.z = (unsigned int)(hi ? b2 : a2);
        u.w = (unsigned int)(hi ? b3 : a3);
        union { uint4 u4; bf16x8 bf; } cv; cv.u4 = u;
        // O^T += V^T . P^T  (A = Vt rows d, B = P^T)
#pragma unroll
        for (int jn = 0; jn < 4; ++jn)
          o[jn] = __builtin_amdgcn_mfma_f32_16x16x32_bf16(vf[kk][jn], cv.bf, o[jn], 0, 0, 0);
      }
    }
  }

  writeout(qw);                               // light strip
}

// proj: A = Yw bf16 (async staging), B = Wp f32 (register-convert), f32 out.
__global__ __launch_bounds__(256) void proj_gemm(
    const unsigned short* __restrict__ Y,
    const float* __restrict__ Wp, const float* __restrict__ bp,
    float* __restrict__ out)
{
  __shared__ __align__(16) unsigned short As[4096];
  __shared__ __align__(16) unsigned short Bs[4096];
  const int tid  = threadIdx.x;
  const int wave = tid >> 6;
  const int lane = tid & 63;
  const int m16  = lane & 15;
  const int quad = lane >> 4;
  const int row0 = blockIdx.x * 128;
  const int col0 = blockIdx.y * 128;
  const int wm = (wave >> 1) * 64;
  const int wn = (wave & 1) * 64;

  f32x4 acc[4][4] = {};

  const int c0 = tid, c1 = 256 + tid;
  const unsigned short* Ag0 = Y + (size_t)(row0 + (c0 >> 2)) * Cc + (c0 & 3) * 8;
  const unsigned short* Ag1 = Y + (size_t)(row0 + (c1 >> 2)) * Cc + (c1 & 3) * 8;
  const float* Bg0 = Wp + (size_t)(col0 + (c0 >> 2)) * Cc + (c0 & 3) * 8;
  const float* Bg1 = Wp + (size_t)(col0 + (c1 >> 2)) * Cc + (c1 & 3) * 8;
  char* Al0 = (char*)As + wave * 1024;
  char* Al1 = (char*)As + 4096 + wave * 1024;

  uint4 b0 = ldconv_f32(Bg0);
  uint4 b1 = ldconv_f32(Bg1);

  for (int k0 = 0; k0 < Cc; k0 += 32) {
    __syncthreads();
    async_copy16(Al0, Ag0 + k0);
    async_copy16(Al1, Ag1 + k0);
    *(uint4*)(Bs + (size_t)c0 * 8) = b0;
    *(uint4*)(Bs + (size_t)c1 * 8) = b1;
    __syncthreads();
    if (k0 + 32 < Cc) {
      b0 = ldconv_f32(Bg0 + k0 + 32);
      b1 = ldconv_f32(Bg1 + k0 + 32);
    }
    bf16x8 af[4], bfr[4];
#pragma unroll
    for (int i = 0; i < 4; ++i)
      af[i] = *(const bf16x8*)(As + (wm + i * 16 + m16) * 32 + quad * 8);
#pragma unroll
    for (int j = 0; j < 4; ++j)
      bfr[j] = *(const bf16x8*)(Bs + (wn + j * 16 + m16) * 32 + quad * 8);
#pragma unroll
    for (int i = 0; i < 4; ++i)
#pragma unroll
      for (int j = 0; j < 4; ++j)
        acc[i][j] = __builtin_amdgcn_mfma_f32_16x16x32_bf16(af[i], bfr[j], acc[i][j], 0, 0, 0);
  }

#pragma unroll
  for (int i = 0; i < 4; ++i) {
    const int rbase = row0 + wm + i * 16 + quad * 4;
#pragma unroll
    for (int j = 0; j < 4; ++j) {
      const int col = col0 + wn + j * 16 + m16;
      const float bv = bp[col];
#pragma unroll
      for (int r = 0; r < 4; ++r)
        out[(size_t)(rbase + r) * Cc + col] = acc[i][j][r] + bv;
    }
  }
}

extern "C" void kernel_launch(void* const* d_in, const int* in_sizes, int n_in,
                              void* d_out, int out_size, void* d_ws, size_t ws_size,
                              hipStream_t stream)
{
  const float* x  = (const float*)d_in[0];
  const float* Wq = (const float*)d_in[1];
  const float* bq = (const float*)d_in[2];
  const float* Wk = (const float*)d_in[3];
  const float* bk = (const float*)d_in[4];
  const float* Wv = (const float*)d_in[5];
  const float* bv = (const float*)d_in[6];
  const float* Wp = (const float*)d_in[7];
  const float* bp = (const float*)d_in[8];

  unsigned short* ws  = (unsigned short*)d_ws;
  unsigned short* Qw  = ws;                          // bf16 [8192][1024] (scale folded)
  unsigned short* Kw  = ws + (size_t)1 * XN;         // bf16 [8192][1024]
  unsigned short* Vtw = ws + (size_t)2 * XN;         // bf16 [b*1024 + n][2048]
  unsigned short* Yw  = ws + (size_t)3 * XN;         // bf16 [8192][1024]

  // d_out doubles as bf16 scratch for converted X/Wq/Wk/Wv; proj overwrites last.
  unsigned short* cvt = (unsigned short*)d_out;
  unsigned short* Xb  = cvt;
  unsigned short* Wqb = cvt + XN;
  unsigned short* Wkb = cvt + XN + WN;
  unsigned short* Wvb = cvt + XN + 2 * WN;
  float* out = (float*)d_out;

  convert_all<<<5632, 256, 0, stream>>>(x, Wq, Wk, Wv, cvt);
  qkv_gemm<<<dim3(64, 8, 3), 256, 0, stream>>>(Xb, Wqb, bq, Wkb, bk, Wvb, bv, Qw, Kw, Vtw);
  attn_pair<<<dim3(16, 64), 256, 0, stream>>>(Qw, Kw, Vtw, Yw);
  proj_gemm<<<dim3(64, 8), 256, 0, stream>>>(Yw, Wp, bp, out);
}